// Round 11
// baseline (52645.306 us; speedup 1.0000x reference)
//
#include <hip/hip_runtime.h>

#define NB 256
#define NT 1024

constexpr int BATCH = 1024;
constexpr int TSTEPS = 20;
constexpr int IND = 13;
constexpr int OD = 9;
constexpr int SU = 32;
constexpr int HID = 32;
constexpr int ITERS = 20;
constexpr float LR = 0.1f;
constexpr float AB1 = 0.9f;
constexpr float AB2 = 0.999f;
constexpr float AEPS = 1e-8f;

constexpr unsigned SPIN_CAP = 1u << 27;

// workspace byte offsets
constexpr size_t OFF_CNT   = 0;        // u32 [4]: cnt[2] slot counters, cnt2
constexpr size_t OFF_ERRP  = 3072;     // f32 [NB]
constexpr size_t OFF_PART  = 4096;     // f32 [2][NB][SU]        -> 69632
constexpr size_t OFF_WIHT  = 69632;    // f32 [45][32]           -> 75392
constexpr size_t OFF_WHHT  = 75392;    // f32 [32][32]           -> 79488
constexpr size_t OFF_W2T   = 79488;    // f32 [256][128]         -> 210560
constexpr size_t OFF_W3T   = 210560;   // f32 [256][256]         -> 472704
constexpr size_t OFF_W4T   = 472704;   // f32 [32][256]          -> 505472
constexpr size_t WS_NEEDED = 505472;

// NO __threadfence(): agent-scope acq_rel fences emit buffer_inv on gfx950
// (invalidates XCD L2 -> weight traffic falls to L3). Cross-block data uses
// per-instruction coherent (agent-scope relaxed atomic) ld/st instead.
__device__ __forceinline__ float ld_coh_f32(const float* p) {
  return __hip_atomic_load(p, __ATOMIC_RELAXED, __HIP_MEMORY_SCOPE_AGENT);
}
__device__ __forceinline__ void st_coh_f32(float* p, float v) {
  __hip_atomic_store(p, v, __ATOMIC_RELAXED, __HIP_MEMORY_SCOPE_AGENT);
}

__device__ __forceinline__ void fma4(float4& a, const float4 w, const float h) {
  a.x += w.x * h; a.y += w.y * h; a.z += w.z * h; a.w += w.w * h;
}
__device__ __forceinline__ float dot4(const float4 a, const float4 b) {
  return a.x * b.x + a.y * b.y + a.z * b.z + a.w * b.w;
}

__global__ void prep_kernel(const float* __restrict__ Wih,
                            const float* __restrict__ Whh,
                            const float* __restrict__ W2,
                            const float* __restrict__ W3,
                            const float* __restrict__ W4,
                            char* __restrict__ ws) {
  float* WihT = reinterpret_cast<float*>(ws + OFF_WIHT);
  float* WhhT = reinterpret_cast<float*>(ws + OFF_WHHT);
  float* W2T  = reinterpret_cast<float*>(ws + OFF_W2T);
  float* W3T  = reinterpret_cast<float*>(ws + OFF_W3T);
  float* W4T  = reinterpret_cast<float*>(ws + OFF_W4T);
  int tid = blockIdx.x * blockDim.x + threadIdx.x;
  int nt = gridDim.x * blockDim.x;
  for (int idx = tid; idx < 32 * 45; idx += nt) {
    int i = idx / 45, c = idx % 45;
    WihT[c * 32 + i] = Wih[idx];
  }
  for (int idx = tid; idx < 32 * 32; idx += nt) {
    int i = idx >> 5, j = idx & 31;
    WhhT[j * 32 + i] = Whh[idx];
  }
  for (int idx = tid; idx < 256 * 128; idx += nt) {   // W2T [256][128]
    int k = idx >> 7, j = idx & 127;
    W2T[idx] = W2[j * 256 + k];
  }
  for (int idx = tid; idx < 256 * 256; idx += nt) {   // W3T [256][256]
    int k = idx >> 8, j = idx & 255;
    W3T[idx] = W3[j * 256 + k];
  }
  for (int idx = tid; idx < 32 * 256; idx += nt) {    // W4T [32][256]
    int k = idx >> 8, j = idx & 255;
    W4T[idx] = W4[j * 32 + k];
  }
}

__global__ __launch_bounds__(NT, 4) void emb_kernel(
    const float* __restrict__ X, const float* __restrict__ Y,
    const float* __restrict__ pW1, const float* __restrict__ pb1,
    const float* __restrict__ pW2, const float* __restrict__ pb2,
    const float* __restrict__ pW3, const float* __restrict__ pb3,
    const float* __restrict__ pW4, const float* __restrict__ pb4,
    const float* __restrict__ pWih, const float* __restrict__ pWhh,
    const float* __restrict__ pbih, const float* __restrict__ pbhh,
    const float* __restrict__ pWd, const float* __restrict__ pbd,
    char* __restrict__ ws, float* __restrict__ out) {
  const int tid = threadIdx.x;
  const int bid = blockIdx.x;
  const int row0 = bid * 4;
  // two 512-thread sub-blocks; sub s owns rows {2s, 2s+1}
  const int t  = tid & 511;
  const int rA = (tid >> 9) * 2, rB = rA + 1;

  unsigned* cnt = reinterpret_cast<unsigned*>(ws + OFF_CNT);      // [2] + cnt2
  float* errp = reinterpret_cast<float*>(ws + OFF_ERRP);          // [NB]
  float* part = reinterpret_cast<float*>(ws + OFF_PART);          // [2][NB][SU]
  const float* WihT = reinterpret_cast<const float*>(ws + OFF_WIHT);
  const float* WhhT = reinterpret_cast<const float*>(ws + OFF_WHHT);
  const float* W2T  = reinterpret_cast<const float*>(ws + OFF_W2T);
  const float* W3T  = reinterpret_cast<const float*>(ws + OFF_W3T);
  const float* W4T  = reinterpret_cast<const float*>(ws + OFF_W4T);

  __shared__ alignas(16) float s[4][SU];
  __shared__ alignas(16) float mAd[4][SU];
  __shared__ alignas(16) float vAd[4][SU];
  __shared__ alignas(16) float hOld[4][HID];
  __shared__ alignas(16) float hNew[4][HID];
  __shared__ alignas(16) float h1[4][128];
  __shared__ alignas(16) float h2[4][256];
  __shared__ alignas(16) float h3[4][256];
  __shared__ alignas(16) float wv[4][SU];
  __shared__ alignas(16) float da[4][HID];
  __shared__ alignas(16) float dwb[4][SU];
  __shared__ alignas(16) float dsb[4][SU];
  __shared__ alignas(16) float red2[8192];   // 32 KB k-split partial buffer
  __shared__ float xs[4][IND];
  __shared__ float ysd[4][OD];
  __shared__ float dadec[4][OD];
  __shared__ float red[32][SU];

  auto spin_ge = [&](unsigned* cntp, unsigned tgt) {
    unsigned n = 0;
    while (__hip_atomic_load(cntp, __ATOMIC_RELAXED,
                             __HIP_MEMORY_SCOPE_AGENT) < tgt) {
      __builtin_amdgcn_s_sleep(1);
      if (++n >= SPIN_CAP) break;
    }
  };

  // ---- layer routines. Batch-of-8 NAMED-variable weight loads: the 8 loads
  // are independent and issue back-to-back (first FMA waits at vmcnt(7)),
  // giving ~8 loads in flight per wave WITHOUT addressable arrays.
  // (R9 lesson: pointer-selected register arrays -> scratch -> 72 GB HBM.)

  // L1 fwd: h1[4][128] = relu(s[4][32] @ W1[32][128] + b1)   (small: simple)
  auto fwd_l1 = [&]() {
    if (t < 256) {
      int j0 = (t & 31) * 4, kg = t >> 5;  // 8 kg x 4 k
      float4 aA = {0,0,0,0}, aB = aA;
#pragma unroll
      for (int q = 0; q < 4; ++q) {
        int k = kg * 4 + q;
        float4 w = *reinterpret_cast<const float4*>(pW1 + k * 128 + j0);
        fma4(aA, w, s[rA][k]); fma4(aB, w, s[rB][k]);
      }
      *reinterpret_cast<float4*>(&red2[(kg * 4 + rA) * 128 + j0]) = aA;
      *reinterpret_cast<float4*>(&red2[(kg * 4 + rB) * 128 + j0]) = aB;
    }
    __syncthreads();
    if (tid < 512) {
      int r = tid >> 7, j = tid & 127;
      float sum = pb1[j];
#pragma unroll
      for (int g = 0; g < 8; ++g) sum += red2[(g * 4 + r) * 128 + j];
      h1[r][j] = fmaxf(sum, 0.f);
    }
  };

  // batch-of-8 pipelined accumulate: KN_ k's starting at KOFF_, weight row
  // stride RS_, weights global, activations LDS. Named vars only (no arrays).
#define PIPE_ACC(W_, RS_, HIN_, KOFF_, KN_, AA_, AB_)                          \
  {                                                                            \
    constexpr int NC_ = (KN_) / 8;                                             \
    _Pragma("unroll")                                                          \
    for (int c = 0; c < NC_; ++c) {                                            \
      const float* wp_ = (W_) + ((KOFF_) + c * 8) * (RS_) + j0;                \
      float4 w0_ = *reinterpret_cast<const float4*>(wp_ + 0 * (RS_));          \
      float4 w1_ = *reinterpret_cast<const float4*>(wp_ + 1 * (RS_));          \
      float4 w2_ = *reinterpret_cast<const float4*>(wp_ + 2 * (RS_));          \
      float4 w3_ = *reinterpret_cast<const float4*>(wp_ + 3 * (RS_));          \
      float4 w4_ = *reinterpret_cast<const float4*>(wp_ + 4 * (RS_));          \
      float4 w5_ = *reinterpret_cast<const float4*>(wp_ + 5 * (RS_));          \
      float4 w6_ = *reinterpret_cast<const float4*>(wp_ + 6 * (RS_));          \
      float4 w7_ = *reinterpret_cast<const float4*>(wp_ + 7 * (RS_));          \
      const float* hA_ = (HIN_) + hbaseA + (KOFF_) + c * 8;                    \
      const float* hB_ = (HIN_) + hbaseB + (KOFF_) + c * 8;                    \
      fma4((AA_), w0_, hA_[0]); fma4((AB_), w0_, hB_[0]);                      \
      fma4((AA_), w1_, hA_[1]); fma4((AB_), w1_, hB_[1]);                      \
      fma4((AA_), w2_, hA_[2]); fma4((AB_), w2_, hB_[2]);                      \
      fma4((AA_), w3_, hA_[3]); fma4((AB_), w3_, hB_[3]);                      \
      fma4((AA_), w4_, hA_[4]); fma4((AB_), w4_, hB_[4]);                      \
      fma4((AA_), w5_, hA_[5]); fma4((AB_), w5_, hB_[5]);                      \
      fma4((AA_), w6_, hA_[6]); fma4((AB_), w6_, hB_[6]);                      \
      fma4((AA_), w7_, hA_[7]); fma4((AB_), w7_, hB_[7]);                      \
    }                                                                          \
  }

  // wide fwd: hout[4][256] = relu(hin[4][K] @ W[K][256] + bias), K in {128,256}
  auto fwd_wide = [&](const float* __restrict__ W, const float* __restrict__ bias,
                      const float* hin, int K, float* hout) {
    {
      int j0 = (t & 63) * 4, kg = t >> 6;  // 8 kg
      float4 aA = {0,0,0,0}, aB = aA;
      const int hbaseA = rA * K, hbaseB = rB * K;
      if (K == 128) {
        PIPE_ACC(W, 256, hin, kg * 16, 16, aA, aB);
      } else {
        PIPE_ACC(W, 256, hin, kg * 32, 32, aA, aB);
      }
      *reinterpret_cast<float4*>(&red2[(kg * 4 + rA) * 256 + j0]) = aA;
      *reinterpret_cast<float4*>(&red2[(kg * 4 + rB) * 256 + j0]) = aB;
    }
    __syncthreads();
    {
      int r = tid >> 8, j = tid & 255;
      float s0 = bias[j];
#pragma unroll
      for (int g = 0; g < 8; ++g) s0 += red2[(g * 4 + r) * 256 + j];
      hout[r * 256 + j] = fmaxf(s0, 0.f);
    }
  };

  // L4 fwd: wv[4][32] = h3[4][256] @ W4[256][32] + b4 (linear)
  auto fwd_l4 = [&]() {
    if (t < 128) {
      int j0 = (t & 7) * 4, kg = t >> 3;  // 16 kg x 16 k
      float4 aA = {0,0,0,0}, aB = aA;
      const int hbaseA = rA * 256, hbaseB = rB * 256;
      const float* hin = &h3[0][0];
      PIPE_ACC(pW4, 32, hin, kg * 16, 16, aA, aB);
      *reinterpret_cast<float4*>(&red2[(kg * 4 + rA) * 32 + j0]) = aA;
      *reinterpret_cast<float4*>(&red2[(kg * 4 + rB) * 32 + j0]) = aB;
    }
    __syncthreads();
    if (tid < 128) {
      int r = tid >> 5, j = tid & 31;
      float sum = pb4[j];
#pragma unroll
      for (int g = 0; g < 16; ++g) sum += red2[(g * 4 + r) * 32 + j];
      wv[r][j] = sum;
    }
  };

  // RNN cell fwd
  auto rnn_fwd = [&]() {
    if (tid < 128) {
      int r = tid >> 5, i = tid & 31;
      float a = pbih[i] + pbhh[i];
#pragma unroll
      for (int c = 0; c < IND; ++c) a += xs[r][c] * WihT[c * 32 + i];
#pragma unroll 8
      for (int c = 0; c < SU; ++c) a += wv[r][c] * WihT[(13 + c) * 32 + i];
#pragma unroll 8
      for (int j = 0; j < HID; ++j) a += hOld[r][j] * WhhT[j * 32 + i];
      hNew[r][i] = tanhf(a);
    }
  };

  // bwd through 256-wide output with TRANSPOSED weights WT[Kd][256]
  auto bwdT256 = [&](const float* __restrict__ WT, const float* din, int Kd,
                     float* dmask) {
    {
      int j0 = (t & 63) * 4, kg = t >> 6;  // 8 kg
      float4 aA = {0,0,0,0}, aB = aA;
      const int hbaseA = rA * Kd, hbaseB = rB * Kd;
      if (Kd == 32) {
        int kn = 4;
#pragma unroll
        for (int q = 0; q < 4; ++q) {
          int k = kg * kn + q;
          float4 w = *reinterpret_cast<const float4*>(WT + k * 256 + j0);
          fma4(aA, w, din[hbaseA + k]); fma4(aB, w, din[hbaseB + k]);
        }
      } else {
        PIPE_ACC(WT, 256, din, kg * 32, 32, aA, aB);
      }
      *reinterpret_cast<float4*>(&red2[(kg * 4 + rA) * 256 + j0]) = aA;
      *reinterpret_cast<float4*>(&red2[(kg * 4 + rB) * 256 + j0]) = aB;
    }
    __syncthreads();
    {
      int r = tid >> 8, j = tid & 255;
      float s0 = 0.f;
#pragma unroll
      for (int g = 0; g < 8; ++g) s0 += red2[(g * 4 + r) * 256 + j];
      float m0 = dmask[r * 256 + j];
      dmask[r * 256 + j] = (m0 > 0.f) ? s0 : 0.f;
    }
  };

  // dh1[r][j<128] = mask(h1) * sum_{k<256} dh2[r][k] W2T[k*128+j]
  auto bwd_dh1 = [&]() {
    {
      int j0 = (t & 31) * 4, kg = t >> 5;  // 16 kg x 16 k
      float4 aA = {0,0,0,0}, aB = aA;
      const int hbaseA = rA * 256, hbaseB = rB * 256;
      const float* hin = &h2[0][0];
      PIPE_ACC(W2T, 128, hin, kg * 16, 16, aA, aB);
      *reinterpret_cast<float4*>(&red2[(kg * 4 + rA) * 128 + j0]) = aA;
      *reinterpret_cast<float4*>(&red2[(kg * 4 + rB) * 128 + j0]) = aB;
    }
    __syncthreads();
    if (tid < 512) {
      int r = tid >> 7, j = tid & 127;
      float sum = 0.f;
#pragma unroll
      for (int g = 0; g < 16; ++g) sum += red2[(g * 4 + r) * 128 + j];
      h1[r][j] = (h1[r][j] > 0.f) ? sum : 0.f;
    }
  };

  // ds[r][k<32] = sum_{j<128} dh1[r][j] W1[k*128+j]   (small: simple)
  auto bwd_ds = [&]() {
    if (t < 256) {
      int k0 = (t & 7) * 4, jg = t >> 3;
      int j0 = jg * 4;
      float4 gA = *reinterpret_cast<const float4*>(&h1[rA][j0]);
      float4 gB = *reinterpret_cast<const float4*>(&h1[rB][j0]);
      float4 aA, aB;
      float* A = &aA.x; float* Bp = &aB.x;
#pragma unroll
      for (int q = 0; q < 4; ++q) {
        int k = k0 + q;
        float4 w = *reinterpret_cast<const float4*>(pW1 + k * 128 + j0);
        A[q] = dot4(w, gA); Bp[q] = dot4(w, gB);
      }
      *reinterpret_cast<float4*>(&red2[jg * 128 + rA * 32 + k0]) = aA;
      *reinterpret_cast<float4*>(&red2[jg * 128 + rB * 32 + k0]) = aB;
    }
    __syncthreads();
    if (tid < 128) {
      int r = tid >> 5, k = tid & 31;
      float sum = 0.f;
#pragma unroll
      for (int g = 0; g < 32; ++g) sum += red2[g * 128 + r * 32 + k];
      dsb[r][k] = sum;
    }
  };

  auto publish = [&](int pslot) {
    __syncthreads();
    if (tid < SU) {
      st_coh_f32(&part[(size_t)pslot * NB * SU + (size_t)bid * SU + tid],
                 s[0][tid] + s[1][tid] + s[2][tid] + s[3][tid]);
    }
    if (tid == 0)
      __hip_atomic_fetch_add(&cnt[pslot], 1u, __ATOMIC_RELEASE,
                             __HIP_MEMORY_SCOPE_AGENT);
  };

  // ---- init
  if (tid < 128) { int r = tid >> 5, c = tid & 31; s[r][c] = 0.f; }
  publish(0);

  // ---- outer timesteps
  for (int ts = 0; ts < TSTEPS; ++ts) {
    if (tid < 4 * IND) {
      int r = tid / IND, c = tid % IND;
      xs[r][c] = X[(size_t)ts * BATCH * IND + (size_t)(row0 + r) * IND + c];
    }
    if (tid >= 64 && tid < 64 + 4 * OD) {
      int q = tid - 64; int r = q / OD, c = q % OD;
      ysd[r][c] = Y[(size_t)ts * BATCH * OD + (size_t)(row0 + r) * OD + c];
    }
    if (tid >= 128 && tid < 256) {
      int q = tid - 128; int r = q >> 5, c = q & 31;
      mAd[r][c] = 0.f; vAd[r][c] = 0.f; hOld[r][c] = 0.f;
    }
    float pb1t = 1.f, pb2t = 1.f;

    for (int it = 0; it < ITERS; ++it) {
      const int gi = ts * ITERS + it;
      const int p = gi & 1;
      pb1t *= AB1; pb2t *= AB2;

      // ---- forward
      fwd_l1(); __syncthreads();
      fwd_wide(pW2, pb2, &h1[0][0], 128, &h2[0][0]); __syncthreads();
      fwd_wide(pW3, pb3, &h2[0][0], 256, &h3[0][0]); __syncthreads();
      fwd_l4(); __syncthreads();
      rnn_fwd(); __syncthreads();

      if (tid < 36) {
        int r = tid / OD, d = tid % OD;
        float adec = pbd[d];
#pragma unroll
        for (int i = 0; i < HID; ++i) adec += hNew[r][i] * pWd[i * OD + d];
        float pr = fmaxf(adec, 0.f);
        dadec[r][d] = (adec > 0.f) ? (2.f / 1024.f) * (pr - ysd[r][d]) : 0.f;
      }
      __syncthreads();

      if (tid < 128) {
        int r = tid >> 5, i = tid & 31;
        float t1 = 0.f;
#pragma unroll
        for (int d = 0; d < OD; ++d) t1 += dadec[r][d] * pWd[i * OD + d];
        float hn = hNew[r][i];
        da[r][i] = t1 * (1.f - hn * hn);
      }
      __syncthreads();

      if (tid < 128) {
        int r = tid >> 5, k = tid & 31;
        float t2 = 0.f;
#pragma unroll 8
        for (int i = 0; i < HID; ++i) t2 += da[r][i] * WihT[(13 + k) * 32 + i];
        dwb[r][k] = t2;
      }
      __syncthreads();

      // ---- backward
      bwdT256(W4T, &dwb[0][0], 32, &h3[0][0]); __syncthreads();
      bwdT256(W3T, &h3[0][0], 256, &h2[0][0]); __syncthreads();
      bwd_dh1(); __syncthreads();
      bwd_ds(); __syncthreads();

      // ---- handshake LATE (mu only needed by Adam)
      if (tid == 0) spin_ge(&cnt[p], (unsigned)(gi / 2 + 1) * (unsigned)NB);
      __syncthreads();

      {
        int c = tid & 31, grp = tid >> 5;
        const float* P = part + (size_t)p * NB * SU;
        float sum = 0.f;
#pragma unroll
        for (int b2 = grp * 8; b2 < grp * 8 + 8; ++b2)
          sum += ld_coh_f32(&P[b2 * SU + c]);
        red[grp][c] = sum;
      }
      __syncthreads();

      if (tid < 128) {
        int r = tid >> 5, c = tid & 31;
        float msum = 0.f;
#pragma unroll
        for (int g = 0; g < 32; ++g) msum += red[g][c];
        float muc = msum * (1.f / 1024.f);
        float sv = s[r][c];
        float g = dsb[r][c] + (sv - muc) * (2.f / 1023.f) + sv * (2e-4f / 1024.f);
        float m2 = AB1 * mAd[r][c] + (1.f - AB1) * g;
        float v2 = AB2 * vAd[r][c] + (1.f - AB2) * g * g;
        mAd[r][c] = m2; vAd[r][c] = v2;
        float mh = m2 / (1.f - pb1t);
        float vh = v2 / (1.f - pb2t);
        s[r][c] = sv - LR * mh / (sqrtf(vh) + AEPS);
        hOld[r][c] = hNew[r][c];
      }

      publish((gi + 1) & 1);
    }
  }

  // ---- final evaluation
  fwd_l1(); __syncthreads();
  fwd_wide(pW2, pb2, &h1[0][0], 128, &h2[0][0]); __syncthreads();
  fwd_wide(pW3, pb3, &h2[0][0], 256, &h3[0][0]); __syncthreads();
  fwd_l4(); __syncthreads();

  if (tid < 128) { int r = tid >> 5, i = tid & 31; hOld[r][i] = 0.f; }
  __syncthreads();

  float errACC = 0.f;
  for (int t2 = 0; t2 < TSTEPS; ++t2) {
    if (tid < 4 * IND) {
      int r = tid / IND, c = tid % IND;
      xs[r][c] = X[(size_t)t2 * BATCH * IND + (size_t)(row0 + r) * IND + c];
    }
    __syncthreads();
    rnn_fwd(); __syncthreads();
    if (tid < 36) {
      int r = tid / OD, d = tid % OD;
      float adec = pbd[d];
#pragma unroll
      for (int i = 0; i < HID; ++i) adec += hNew[r][i] * pWd[i * OD + d];
      float pr = fmaxf(adec, 0.f);
      float e = pr - Y[(size_t)t2 * BATCH * OD + (size_t)(row0 + r) * OD + d];
      errACC += e * e;
    }
    if (tid < 128) { int r = tid >> 5, i = tid & 31; hOld[r][i] = hNew[r][i]; }
    __syncthreads();
  }

  if (tid < 36) (&red[0][0])[tid] = errACC;
  __syncthreads();
  if (tid == 0) {
    float sum = 0.f;
    for (int q = 0; q < 36; ++q) sum += (&red[0][0])[q];
    st_coh_f32(&errp[bid], sum);
    __hip_atomic_fetch_add(&cnt[2], 1u, __ATOMIC_RELEASE,
                           __HIP_MEMORY_SCOPE_AGENT);
  }

  if (bid == 0) {
    if (tid == 0) {
      spin_ge(&cnt[2], (unsigned)NB);
      spin_ge(&cnt[0], (unsigned)(TSTEPS * ITERS / 2 + 1) * (unsigned)NB);
    }
    __syncthreads();
    if (tid == 0) {
      float sum = 0.f;
      for (int b = 0; b < NB; ++b) sum += ld_coh_f32(&errp[b]);
      out[0] = sum * (1.f / 1024.f);
    }
    if (tid >= 64 && tid < 96) {
      int c = tid - 64;
      float sum = 0.f;
      for (int b = 0; b < NB; ++b)
        sum += ld_coh_f32(&part[(size_t)b * SU + c]);
      out[1 + c] = sum * (1.f / 1024.f);
    }
  }
}

extern "C" void kernel_launch(void* const* d_in, const int* in_sizes, int n_in,
                              void* d_out, int out_size, void* d_ws, size_t ws_size,
                              hipStream_t stream) {
  (void)in_sizes; (void)n_in; (void)out_size;
  if (ws_size < WS_NEEDED) return;

  const float* X   = (const float*)d_in[0];
  const float* Y   = (const float*)d_in[1];
  const float* W1  = (const float*)d_in[2];
  const float* b1  = (const float*)d_in[3];
  const float* W2  = (const float*)d_in[4];
  const float* b2  = (const float*)d_in[5];
  const float* W3  = (const float*)d_in[6];
  const float* b3  = (const float*)d_in[7];
  const float* W4  = (const float*)d_in[8];
  const float* b4  = (const float*)d_in[9];
  const float* Wih = (const float*)d_in[10];
  const float* Whh = (const float*)d_in[11];
  const float* bih = (const float*)d_in[12];
  const float* bhh = (const float*)d_in[13];
  const float* Wd  = (const float*)d_in[14];
  const float* bd  = (const float*)d_in[15];

  hipMemsetAsync(d_ws, 0, 3072, stream);
  prep_kernel<<<128, 256, 0, stream>>>(Wih, Whh, W2, W3, W4, (char*)d_ws);
  emb_kernel<<<NB, NT, 0, stream>>>(X, Y, W1, b1, W2, b2, W3, b3, W4, b4,
                                    Wih, Whh, bih, bhh, Wd, bd,
                                    (char*)d_ws, (float*)d_out);
}

// Round 12
// 33055.240 us; speedup vs baseline: 1.5926x; 1.5926x over previous
//
#include <hip/hip_runtime.h>

#define NB 512
#define NT 1024

constexpr int BATCH = 1024;
constexpr int TSTEPS = 20;
constexpr int IND = 13;
constexpr int OD = 9;
constexpr int SU = 32;
constexpr int HID = 32;
constexpr int ITERS = 20;
constexpr float LR = 0.1f;
constexpr float AB1 = 0.9f;
constexpr float AB2 = 0.999f;
constexpr float AEPS = 1e-8f;

constexpr unsigned SPIN_CAP = 1u << 27;

// workspace byte offsets
constexpr size_t OFF_CNT   = 0;        // u32 [4]: cnt[2] slot counters, cnt2
constexpr size_t OFF_ERRP  = 3072;     // f32 [NB]               -> 5120
constexpr size_t OFF_PART  = 5120;     // f32 [2][NB][SU]        -> 136192
constexpr size_t OFF_WIHT  = 136192;   // f32 [45][32]           -> 141952
constexpr size_t OFF_WHHT  = 141952;   // f32 [32][32]           -> 146048
constexpr size_t OFF_W2T   = 146048;   // f32 [256][128]         -> 277120
constexpr size_t OFF_W3T   = 277120;   // f32 [256][256]         -> 539264
constexpr size_t OFF_W4T   = 539264;   // f32 [32][256]          -> 572032
constexpr size_t WS_NEEDED = 572032;

// NO __threadfence(): agent-scope acq_rel fences emit buffer_inv on gfx950
// (invalidates XCD L2 -> weight traffic falls to L3). Cross-block data uses
// per-instruction coherent (agent-scope relaxed atomic) ld/st instead.
__device__ __forceinline__ float ld_coh_f32(const float* p) {
  return __hip_atomic_load(p, __ATOMIC_RELAXED, __HIP_MEMORY_SCOPE_AGENT);
}
__device__ __forceinline__ void st_coh_f32(float* p, float v) {
  __hip_atomic_store(p, v, __ATOMIC_RELAXED, __HIP_MEMORY_SCOPE_AGENT);
}

__device__ __forceinline__ void fma4(float4& a, const float4 w, const float h) {
  a.x += w.x * h; a.y += w.y * h; a.z += w.z * h; a.w += w.w * h;
}
__device__ __forceinline__ float dot4(const float4 a, const float4 b) {
  return a.x * b.x + a.y * b.y + a.z * b.z + a.w * b.w;
}

__global__ void prep_kernel(const float* __restrict__ Wih,
                            const float* __restrict__ Whh,
                            const float* __restrict__ W2,
                            const float* __restrict__ W3,
                            const float* __restrict__ W4,
                            char* __restrict__ ws) {
  float* WihT = reinterpret_cast<float*>(ws + OFF_WIHT);
  float* WhhT = reinterpret_cast<float*>(ws + OFF_WHHT);
  float* W2T  = reinterpret_cast<float*>(ws + OFF_W2T);
  float* W3T  = reinterpret_cast<float*>(ws + OFF_W3T);
  float* W4T  = reinterpret_cast<float*>(ws + OFF_W4T);
  int tid = blockIdx.x * blockDim.x + threadIdx.x;
  int nt = gridDim.x * blockDim.x;
  for (int idx = tid; idx < 32 * 45; idx += nt) {
    int i = idx / 45, c = idx % 45;
    WihT[c * 32 + i] = Wih[idx];
  }
  for (int idx = tid; idx < 32 * 32; idx += nt) {
    int i = idx >> 5, j = idx & 31;
    WhhT[j * 32 + i] = Whh[idx];
  }
  for (int idx = tid; idx < 256 * 128; idx += nt) {   // W2T [256][128]
    int k = idx >> 7, j = idx & 127;
    W2T[idx] = W2[j * 256 + k];
  }
  for (int idx = tid; idx < 256 * 256; idx += nt) {   // W3T [256][256]
    int k = idx >> 8, j = idx & 255;
    W3T[idx] = W3[j * 256 + k];
  }
  for (int idx = tid; idx < 32 * 256; idx += nt) {    // W4T [32][256]
    int k = idx >> 8, j = idx & 255;
    W4T[idx] = W4[j * 32 + k];
  }
}

// 2 rows per block, 512 blocks, 1024 threads; min 8 waves/EU => 2 blocks/CU
// co-resident (VGPR forced <=64), 32 waves/CU for latency hiding.
__global__ __launch_bounds__(NT, 8) void emb_kernel(
    const float* __restrict__ X, const float* __restrict__ Y,
    const float* __restrict__ pW1, const float* __restrict__ pb1,
    const float* __restrict__ pW2, const float* __restrict__ pb2,
    const float* __restrict__ pW3, const float* __restrict__ pb3,
    const float* __restrict__ pW4, const float* __restrict__ pb4,
    const float* __restrict__ pWih, const float* __restrict__ pWhh,
    const float* __restrict__ pbih, const float* __restrict__ pbhh,
    const float* __restrict__ pWd, const float* __restrict__ pbd,
    char* __restrict__ ws, float* __restrict__ out) {
  const int tid = threadIdx.x;
  const int bid = blockIdx.x;
  const int row0 = bid * 2;

  unsigned* cnt = reinterpret_cast<unsigned*>(ws + OFF_CNT);      // [2] + cnt2
  float* errp = reinterpret_cast<float*>(ws + OFF_ERRP);          // [NB]
  float* part = reinterpret_cast<float*>(ws + OFF_PART);          // [2][NB][SU]
  const float* WihT = reinterpret_cast<const float*>(ws + OFF_WIHT);
  const float* WhhT = reinterpret_cast<const float*>(ws + OFF_WHHT);
  const float* W2T  = reinterpret_cast<const float*>(ws + OFF_W2T);
  const float* W3T  = reinterpret_cast<const float*>(ws + OFF_W3T);
  const float* W4T  = reinterpret_cast<const float*>(ws + OFF_W4T);

  __shared__ alignas(16) float s[2][SU];
  __shared__ alignas(16) float mAd[2][SU];
  __shared__ alignas(16) float vAd[2][SU];
  __shared__ alignas(16) float hOld[2][HID];
  __shared__ alignas(16) float hNew[2][HID];
  __shared__ alignas(16) float h1[2][128];
  __shared__ alignas(16) float h2[2][256];
  __shared__ alignas(16) float h3[2][256];
  __shared__ alignas(16) float wv[2][SU];
  __shared__ alignas(16) float da[2][HID];
  __shared__ alignas(16) float dwb[2][SU];
  __shared__ alignas(16) float dsb[2][SU];
  __shared__ alignas(16) float red2[8192];   // 32 KB k-split partial buffer
  __shared__ float xs[2][IND];
  __shared__ float ysd[2][OD];
  __shared__ float dadec[2][OD];
  __shared__ float red[32][SU];

  auto spin_ge = [&](unsigned* cntp, unsigned tgt) {
    unsigned n = 0;
    while (__hip_atomic_load(cntp, __ATOMIC_RELAXED,
                             __HIP_MEMORY_SCOPE_AGENT) < tgt) {
      __builtin_amdgcn_s_sleep(1);
      if (++n >= SPIN_CAP) break;
    }
  };

  // ---- layer routines: R7-proven pattern (one float4 weight load -> 2 fma4),
  // k-split doubled (16/32 groups) since 1024 threads now serve 2 rows.

  // L1 fwd: h1[2][128] = relu(s[2][32] @ W1[32][128] + b1)
  auto fwd_l1 = [&]() {
    {
      int j0 = (tid & 31) * 4, k = tid >> 5;  // 32 k-groups x 1 k
      float4 a0 = {0, 0, 0, 0}, a1 = a0;
      float4 w = *reinterpret_cast<const float4*>(pW1 + k * 128 + j0);
      fma4(a0, w, s[0][k]); fma4(a1, w, s[1][k]);
      *reinterpret_cast<float4*>(&red2[(k * 2 + 0) * 128 + j0]) = a0;
      *reinterpret_cast<float4*>(&red2[(k * 2 + 1) * 128 + j0]) = a1;
    }
    __syncthreads();
    if (tid < 256) {
      int r = tid >> 7, j = tid & 127;
      float sum = pb1[j];
#pragma unroll 8
      for (int g = 0; g < 32; ++g) sum += red2[(g * 2 + r) * 128 + j];
      h1[r][j] = fmaxf(sum, 0.f);
    }
  };

  // wide fwd: hout[2][256] = relu(hin[2][K] @ W[K][256] + bias), K in {128,256}
  auto fwd_wide = [&](const float* __restrict__ W, const float* __restrict__ bias,
                      const float* hin, int K, float* hout) {
    {
      int j0 = (tid & 63) * 4, kg = tid >> 6;  // 16 kg
      int kn = K >> 4;                          // 8 or 16
      float4 a0 = {0, 0, 0, 0}, a1 = a0;
#pragma unroll 8
      for (int q = 0; q < kn; ++q) {
        int k = kg * kn + q;
        float4 w = *reinterpret_cast<const float4*>(W + k * 256 + j0);
        fma4(a0, w, hin[k]); fma4(a1, w, hin[K + k]);
      }
      *reinterpret_cast<float4*>(&red2[(kg * 2 + 0) * 256 + j0]) = a0;
      *reinterpret_cast<float4*>(&red2[(kg * 2 + 1) * 256 + j0]) = a1;
    }
    __syncthreads();
    if (tid < 512) {
      int r = tid >> 8, j = tid & 255;
      float s0 = bias[j];
#pragma unroll
      for (int g = 0; g < 16; ++g) s0 += red2[(g * 2 + r) * 256 + j];
      hout[r * 256 + j] = fmaxf(s0, 0.f);
    }
  };

  // L4 fwd: wv[2][32] = h3[2][256] @ W4[256][32] + b4 (linear)
  auto fwd_l4 = [&]() {
    if (tid < 256) {
      int j0 = (tid & 7) * 4, kg = tid >> 3;  // 32 kg x 8 k
      float4 a0 = {0, 0, 0, 0}, a1 = a0;
#pragma unroll
      for (int q = 0; q < 8; ++q) {
        int k = kg * 8 + q;
        float4 w = *reinterpret_cast<const float4*>(pW4 + k * 32 + j0);
        fma4(a0, w, h3[0][k]); fma4(a1, w, h3[1][k]);
      }
      *reinterpret_cast<float4*>(&red2[(kg * 2 + 0) * 32 + j0]) = a0;
      *reinterpret_cast<float4*>(&red2[(kg * 2 + 1) * 32 + j0]) = a1;
    }
    __syncthreads();
    if (tid < 64) {
      int r = tid >> 5, j = tid & 31;
      float sum = pb4[j];
#pragma unroll 8
      for (int g = 0; g < 32; ++g) sum += red2[(g * 2 + r) * 32 + j];
      wv[r][j] = sum;
    }
  };

  // RNN cell fwd
  auto rnn_fwd = [&]() {
    if (tid < 64) {
      int r = tid >> 5, i = tid & 31;
      float a = pbih[i] + pbhh[i];
#pragma unroll
      for (int c = 0; c < IND; ++c) a += xs[r][c] * WihT[c * 32 + i];
#pragma unroll 8
      for (int c = 0; c < SU; ++c) a += wv[r][c] * WihT[(13 + c) * 32 + i];
#pragma unroll 8
      for (int j = 0; j < HID; ++j) a += hOld[r][j] * WhhT[j * 32 + i];
      hNew[r][i] = tanhf(a);
    }
  };

  // bwd through 256-wide output with TRANSPOSED weights WT[Kd][256]
  auto bwdT256 = [&](const float* __restrict__ WT, const float* din, int Kd,
                     float* dmask) {
    {
      int j0 = (tid & 63) * 4, kg = tid >> 6;  // 16 kg
      int kn = Kd >> 4;                         // 2 or 16
      float4 a0 = {0, 0, 0, 0}, a1 = a0;
#pragma unroll 8
      for (int q = 0; q < kn; ++q) {
        int k = kg * kn + q;
        float4 w = *reinterpret_cast<const float4*>(WT + k * 256 + j0);
        fma4(a0, w, din[k]); fma4(a1, w, din[Kd + k]);
      }
      *reinterpret_cast<float4*>(&red2[(kg * 2 + 0) * 256 + j0]) = a0;
      *reinterpret_cast<float4*>(&red2[(kg * 2 + 1) * 256 + j0]) = a1;
    }
    __syncthreads();
    if (tid < 512) {
      int r = tid >> 8, j = tid & 255;
      float s0 = 0.f;
#pragma unroll
      for (int g = 0; g < 16; ++g) s0 += red2[(g * 2 + r) * 256 + j];
      float m0 = dmask[r * 256 + j];
      dmask[r * 256 + j] = (m0 > 0.f) ? s0 : 0.f;
    }
  };

  // dh1[r][j<128] = mask(h1) * sum_{k<256} dh2[r][k] W2T[k*128+j]
  auto bwd_dh1 = [&]() {
    {
      int j0 = (tid & 31) * 4, kg = tid >> 5;  // 32 kg x 8 k
      float4 a0 = {0, 0, 0, 0}, a1 = a0;
#pragma unroll
      for (int q = 0; q < 8; ++q) {
        int k = kg * 8 + q;
        float4 w = *reinterpret_cast<const float4*>(W2T + k * 128 + j0);
        fma4(a0, w, h2[0][k]); fma4(a1, w, h2[1][k]);
      }
      *reinterpret_cast<float4*>(&red2[(kg * 2 + 0) * 128 + j0]) = a0;
      *reinterpret_cast<float4*>(&red2[(kg * 2 + 1) * 128 + j0]) = a1;
    }
    __syncthreads();
    if (tid < 256) {
      int r = tid >> 7, j = tid & 127;
      float sum = 0.f;
#pragma unroll 8
      for (int g = 0; g < 32; ++g) sum += red2[(g * 2 + r) * 128 + j];
      h1[r][j] = (h1[r][j] > 0.f) ? sum : 0.f;
    }
  };

  // ds[r][k<32] = sum_{j<128} dh1[r][j] W1[k*128+j]
  auto bwd_ds = [&]() {
    if (tid < 256) {
      int k0 = (tid & 7) * 4, jg = tid >> 3;  // 32 j-groups x 4 j
      int j0 = jg * 4;
      float4 gA = *reinterpret_cast<const float4*>(&h1[0][j0]);
      float4 gB = *reinterpret_cast<const float4*>(&h1[1][j0]);
      float4 aA, aB;
      float* A = &aA.x; float* Bp = &aB.x;
#pragma unroll
      for (int q = 0; q < 4; ++q) {
        int k = k0 + q;
        float4 w = *reinterpret_cast<const float4*>(pW1 + k * 128 + j0);
        A[q] = dot4(w, gA); Bp[q] = dot4(w, gB);
      }
      *reinterpret_cast<float4*>(&red2[jg * 64 + 0 * 32 + k0]) = aA;
      *reinterpret_cast<float4*>(&red2[jg * 64 + 1 * 32 + k0]) = aB;
    }
    __syncthreads();
    if (tid < 64) {
      int r = tid >> 5, k = tid & 31;
      float sum = 0.f;
#pragma unroll 8
      for (int g = 0; g < 32; ++g) sum += red2[g * 64 + r * 32 + k];
      dsb[r][k] = sum;
    }
  };

  auto publish = [&](int pslot) {
    __syncthreads();
    if (tid < SU) {
      st_coh_f32(&part[(size_t)pslot * NB * SU + (size_t)bid * SU + tid],
                 s[0][tid] + s[1][tid]);
    }
    if (tid == 0)
      __hip_atomic_fetch_add(&cnt[pslot], 1u, __ATOMIC_RELEASE,
                             __HIP_MEMORY_SCOPE_AGENT);
  };

  // ---- init
  if (tid < 64) { int r = tid >> 5, c = tid & 31; s[r][c] = 0.f; }
  publish(0);

  // ---- outer timesteps
  for (int ts = 0; ts < TSTEPS; ++ts) {
    if (tid < 2 * IND) {
      int r = tid / IND, c = tid % IND;
      xs[r][c] = X[(size_t)ts * BATCH * IND + (size_t)(row0 + r) * IND + c];
    }
    if (tid >= 64 && tid < 64 + 2 * OD) {
      int q = tid - 64; int r = q / OD, c = q % OD;
      ysd[r][c] = Y[(size_t)ts * BATCH * OD + (size_t)(row0 + r) * OD + c];
    }
    if (tid >= 128 && tid < 192) {
      int q = tid - 128; int r = q >> 5, c = q & 31;
      mAd[r][c] = 0.f; vAd[r][c] = 0.f; hOld[r][c] = 0.f;
    }
    float pb1t = 1.f, pb2t = 1.f;

    for (int it = 0; it < ITERS; ++it) {
      const int gi = ts * ITERS + it;
      const int p = gi & 1;
      pb1t *= AB1; pb2t *= AB2;

      // ---- forward
      fwd_l1(); __syncthreads();
      fwd_wide(pW2, pb2, &h1[0][0], 128, &h2[0][0]); __syncthreads();
      fwd_wide(pW3, pb3, &h2[0][0], 256, &h3[0][0]); __syncthreads();
      fwd_l4(); __syncthreads();
      rnn_fwd(); __syncthreads();

      if (tid < 2 * OD) {  // decoder + d(err)/d(adec)
        int r = tid / OD, d = tid % OD;
        float adec = pbd[d];
#pragma unroll
        for (int i = 0; i < HID; ++i) adec += hNew[r][i] * pWd[i * OD + d];
        float pr = fmaxf(adec, 0.f);
        dadec[r][d] = (adec > 0.f) ? (2.f / 1024.f) * (pr - ysd[r][d]) : 0.f;
      }
      __syncthreads();

      if (tid < 64) {  // d h_new -> da (through tanh)
        int r = tid >> 5, i = tid & 31;
        float t1 = 0.f;
#pragma unroll
        for (int d = 0; d < OD; ++d) t1 += dadec[r][d] * pWd[i * OD + d];
        float hn = hNew[r][i];
        da[r][i] = t1 * (1.f - hn * hn);
      }
      __syncthreads();

      if (tid < 64) {  // dw_k = sum_i da_i Wih[i][13+k]
        int r = tid >> 5, k = tid & 31;
        float t2 = 0.f;
#pragma unroll 8
        for (int i = 0; i < HID; ++i) t2 += da[r][i] * WihT[(13 + k) * 32 + i];
        dwb[r][k] = t2;
      }
      __syncthreads();

      // ---- backward
      bwdT256(W4T, &dwb[0][0], 32, &h3[0][0]); __syncthreads();
      bwdT256(W3T, &h3[0][0], 256, &h2[0][0]); __syncthreads();
      bwd_dh1(); __syncthreads();
      bwd_ds(); __syncthreads();

      // ---- handshake LATE (mu only needed by Adam)
      if (tid == 0) spin_ge(&cnt[p], (unsigned)(gi / 2 + 1) * (unsigned)NB);
      __syncthreads();

      {  // mu partial reduction: 32 groups x 16 blocks
        int c = tid & 31, grp = tid >> 5;
        const float* P = part + (size_t)p * NB * SU;
        float sum = 0.f;
#pragma unroll
        for (int b2 = grp * 16; b2 < grp * 16 + 16; ++b2)
          sum += ld_coh_f32(&P[b2 * SU + c]);
        red[grp][c] = sum;
      }
      __syncthreads();

      if (tid < 64) {  // Adam update + hidden carry
        int r = tid >> 5, c = tid & 31;
        float msum = 0.f;
#pragma unroll 8
        for (int g = 0; g < 32; ++g) msum += red[g][c];
        float muc = msum * (1.f / 1024.f);
        float sv = s[r][c];
        float g = dsb[r][c] + (sv - muc) * (2.f / 1023.f) + sv * (2e-4f / 1024.f);
        float m2 = AB1 * mAd[r][c] + (1.f - AB1) * g;
        float v2 = AB2 * vAd[r][c] + (1.f - AB2) * g * g;
        mAd[r][c] = m2; vAd[r][c] = v2;
        float mh = m2 / (1.f - pb1t);
        float vh = v2 / (1.f - pb2t);
        s[r][c] = sv - LR * mh / (sqrtf(vh) + AEPS);
        hOld[r][c] = hNew[r][c];
      }

      publish((gi + 1) & 1);
    }
  }

  // ---- final evaluation
  fwd_l1(); __syncthreads();
  fwd_wide(pW2, pb2, &h1[0][0], 128, &h2[0][0]); __syncthreads();
  fwd_wide(pW3, pb3, &h2[0][0], 256, &h3[0][0]); __syncthreads();
  fwd_l4(); __syncthreads();

  if (tid < 64) { int r = tid >> 5, i = tid & 31; hOld[r][i] = 0.f; }
  __syncthreads();

  float errACC = 0.f;
  for (int t2 = 0; t2 < TSTEPS; ++t2) {
    if (tid < 2 * IND) {
      int r = tid / IND, c = tid % IND;
      xs[r][c] = X[(size_t)t2 * BATCH * IND + (size_t)(row0 + r) * IND + c];
    }
    __syncthreads();
    rnn_fwd(); __syncthreads();
    if (tid < 2 * OD) {
      int r = tid / OD, d = tid % OD;
      float adec = pbd[d];
#pragma unroll
      for (int i = 0; i < HID; ++i) adec += hNew[r][i] * pWd[i * OD + d];
      float pr = fmaxf(adec, 0.f);
      float e = pr - Y[(size_t)t2 * BATCH * OD + (size_t)(row0 + r) * OD + d];
      errACC += e * e;
    }
    if (tid < 64) { int r = tid >> 5, i = tid & 31; hOld[r][i] = hNew[r][i]; }
    __syncthreads();
  }

  if (tid < 2 * OD) (&red[0][0])[tid] = errACC;
  __syncthreads();
  if (tid == 0) {
    float sum = 0.f;
    for (int q = 0; q < 2 * OD; ++q) sum += (&red[0][0])[q];
    st_coh_f32(&errp[bid], sum);
    __hip_atomic_fetch_add(&cnt[2], 1u, __ATOMIC_RELEASE,
                           __HIP_MEMORY_SCOPE_AGENT);
  }

  // block 0 produces the 33 outputs
  if (bid == 0) {
    if (tid == 0) {
      spin_ge(&cnt[2], (unsigned)NB);
      // slot 0 publishes: init + ends of odd iters 1..399 = 201 per block
      spin_ge(&cnt[0], (unsigned)(TSTEPS * ITERS / 2 + 1) * (unsigned)NB);
    }
    __syncthreads();
    if (tid == 0) {
      float sum = 0.f;
      for (int b = 0; b < NB; ++b) sum += ld_coh_f32(&errp[b]);
      out[0] = sum * (1.f / 1024.f);
    }
    if (tid >= 64 && tid < 96) {
      int c = tid - 64;
      float sum = 0.f;
      for (int b = 0; b < NB; ++b)
        sum += ld_coh_f32(&part[(size_t)b * SU + c]);
      out[1 + c] = sum * (1.f / 1024.f);
    }
  }
}

extern "C" void kernel_launch(void* const* d_in, const int* in_sizes, int n_in,
                              void* d_out, int out_size, void* d_ws, size_t ws_size,
                              hipStream_t stream) {
  (void)in_sizes; (void)n_in; (void)out_size;
  if (ws_size < WS_NEEDED) return;

  const float* X   = (const float*)d_in[0];
  const float* Y   = (const float*)d_in[1];
  const float* W1  = (const float*)d_in[2];
  const float* b1  = (const float*)d_in[3];
  const float* W2  = (const float*)d_in[4];
  const float* b2  = (const float*)d_in[5];
  const float* W3  = (const float*)d_in[6];
  const float* b3  = (const float*)d_in[7];
  const float* W4  = (const float*)d_in[8];
  const float* b4  = (const float*)d_in[9];
  const float* Wih = (const float*)d_in[10];
  const float* Whh = (const float*)d_in[11];
  const float* bih = (const float*)d_in[12];
  const float* bhh = (const float*)d_in[13];
  const float* Wd  = (const float*)d_in[14];
  const float* bd  = (const float*)d_in[15];

  hipMemsetAsync(d_ws, 0, 3072, stream);
  prep_kernel<<<128, 256, 0, stream>>>(Wih, Whh, W2, W3, W4, (char*)d_ws);
  emb_kernel<<<NB, NT, 0, stream>>>(X, Y, W1, b1, W2, b2, W3, b3, W4, b4,
                                    Wih, Whh, bih, bhh, Wd, bd,
                                    (char*)d_ws, (float*)d_out);
}